// Round 12
// baseline (429.550 us; speedup 1.0000x reference)
//
#include <hip/hip_runtime.h>
#include <math.h>

#define MITEMS 2
#define TILE 512   // 256 * MITEMS
#define NBLK 1024  // co-resident grid: 4 blocks/CU x 256 CUs
#define SUBS 64    // blocks per batch for loss/hist/sum phases

// ---------------------------------------------------------------------------
// ws layout (memset region first):
//   double pconf[B], ploc[B], phard[B] ; int n_pos[B] ; u32 cnt, gen (+pad)
//   u64    prior_fo[B*64]   : packed (iou_bits<<32)|(0xFFFFFFFF-p), atomicMax
//   u32    hist0[B][4096], hist1[B][4096]
//   ---- end memset ----
//   float  conf_neg[B*P]
//   u8     best_u8[B*P]     : bit7 = (best iou >= 0.5), bits0-6 = best obj
// ---------------------------------------------------------------------------

__device__ __forceinline__ unsigned long long umax64(unsigned long long a,
                                                     unsigned long long b) {
  return a > b ? a : b;
}

// Sense-reversing grid barrier. Safe: grid co-resident by construction.
__device__ __forceinline__ void gridbar(unsigned* cnt, unsigned* gen) {
  __syncthreads();
  if (threadIdx.x == 0) {
    const unsigned g =
        __hip_atomic_load(gen, __ATOMIC_RELAXED, __HIP_MEMORY_SCOPE_AGENT);
    __threadfence();  // release: make prior writes visible device-wide
    const unsigned a = atomicAdd(cnt, 1u);
    if (a == (unsigned)NBLK - 1u) {
      __hip_atomic_store(cnt, 0u, __ATOMIC_RELAXED, __HIP_MEMORY_SCOPE_AGENT);
      __threadfence();
      atomicAdd(gen, 1u);
    } else {
      long long guard = 0;
      while (__hip_atomic_load(gen, __ATOMIC_RELAXED,
                               __HIP_MEMORY_SCOPE_AGENT) == g) {
        __builtin_amdgcn_s_sleep(2);
        if (++guard > (1ll << 24)) break;  // safety valve (corrupts, not hangs)
      }
      __threadfence();  // acquire
    }
  }
  __syncthreads();
}

// Cooperative block-wide radix select over BINS bins (descending cumulative).
template <int BINS>
__device__ void block_select(const unsigned* __restrict__ h, int remk,
                             unsigned* s_scan, int* s_out, unsigned* sel,
                             int* remk_o) {
  constexpr int BPT = BINS / 256;
  const int t = threadIdx.x;
  if (t == 0) { s_out[0] = BINS - 1; s_out[1] = 0; }
  unsigned mb[BPT];
  unsigned s = 0;
#pragma unroll
  for (int i = 0; i < BPT; ++i) { mb[i] = h[t * BPT + i]; s += mb[i]; }
  unsigned incl = s;
  s_scan[t] = incl;
  __syncthreads();
  for (int off = 1; off < 256; off <<= 1) {
    const unsigned add = (t >= off) ? s_scan[t - off] : 0u;
    __syncthreads();
    incl += add;
    s_scan[t] = incl;
    __syncthreads();
  }
  const unsigned total = s_scan[255];
  const unsigned R = total - incl;
  if (remk > 0 && R < (unsigned)remk && R + s >= (unsigned)remk) {
    unsigned acc = R;
    int sel_i = t * BPT, rk = 0;
    bool done = false;
#pragma unroll
    for (int i = BPT - 1; i >= 0; --i) {
      if (!done && acc + mb[i] >= (unsigned)remk) {
        sel_i = t * BPT + i;
        rk = remk - (int)acc;
        done = true;
      }
      if (!done) acc += mb[i];
    }
    s_out[0] = sel_i;
    s_out[1] = rk;
  }
  __syncthreads();
  *sel = (unsigned)s_out[0];
  *remk_o = s_out[1];
  __syncthreads();
}

template <int NOBJ, int CC, bool FULL>
__global__ __launch_bounds__(256, 4) void mbl_mega(
    const float* __restrict__ locs, const float* __restrict__ scores,
    const float* __restrict__ boxes, const int* __restrict__ labels,
    const float* __restrict__ priors, unsigned long long* __restrict__ prior_fo,
    unsigned char* __restrict__ best_u8, float* __restrict__ conf_neg,
    unsigned* __restrict__ hist0, unsigned* __restrict__ hist1,
    int* __restrict__ n_pos, double* __restrict__ pconf,
    double* __restrict__ ploc, double* __restrict__ phard,
    unsigned* __restrict__ cnt, unsigned* __restrict__ gen,
    float* __restrict__ out, int P, int n_obj, int B) {
  __shared__ __align__(16) unsigned char smem[23680];
  const int bid = blockIdx.x;
  const int tid = threadIdx.x;

  // ======================= Phase A: match =======================
  {
    float4(*s_box)[2] = (float4(*)[2])smem;                       // NOBJ*32
    unsigned(*s_iou)[264] = (unsigned(*)[264])(smem + 2048);      // 8448
    unsigned(*s_pinv)[264] = (unsigned(*)[264])(smem + 10496);    // 8448
    const int tiles_per_batch = (P + TILE - 1) / TILE;
    const int total_tiles = B * tiles_per_batch;
    const int tpb = (total_tiles + NBLK - 1) / NBLK;
    int cur_b = -1;
    for (int ti = 0; ti < tpb; ++ti) {
      const int t = bid * tpb + ti;
      if (t >= total_tiles) break;
      const int b = t / tiles_per_batch;
      const int tb = t - b * tiles_per_batch;
      __syncthreads();  // previous tile's epilogue readers done
      if (b != cur_b) {
        for (int i = tid; i < NOBJ; i += 256) {
          float4 v0, v1;
          if (i < n_obj) {
            const float* bx = boxes + ((size_t)b * n_obj + i) * 6;
            const float l0 = bx[0], l1 = bx[1], l2 = bx[2];
            const float h0 = bx[3], h1 = bx[4], h2 = bx[5];
            v0 = make_float4(l0, l1, l2, h0);
            v1 = make_float4(h1, h2, ((h0 - l0) * (h1 - l1)) * (h2 - l2), 0.f);
          } else {  // dummy object: iou 0 vs everything
            v0 = make_float4(3e18f, 3e18f, 3e18f, 1e18f);
            v1 = make_float4(1e18f, 1e18f, 0.f, 0.f);
          }
          s_box[i][0] = v0;
          s_box[i][1] = v1;
        }
        cur_b = b;
      }
      __syncthreads();

      const int pbase = tb * TILE;
      float lo0[MITEMS], lo1[MITEMS], lo2[MITEMS], hi0[MITEMS], hi1[MITEMS],
          hi2[MITEMS], vb[MITEMS];
      unsigned invp[MITEMS];
#pragma unroll
      for (int k = 0; k < MITEMS; ++k) {
        const int p = pbase + k * 256 + tid;
        if (FULL || p < P) {
          const float2 q0 = *(const float2*)(priors + (size_t)p * 6);
          const float2 q1 = *(const float2*)(priors + (size_t)p * 6 + 2);
          const float2 q2 = *(const float2*)(priors + (size_t)p * 6 + 4);
          lo0[k] = q0.x - q1.y * 0.5f; hi0[k] = q0.x + q1.y * 0.5f;
          lo1[k] = q0.y - q2.x * 0.5f; hi1[k] = q0.y + q2.x * 0.5f;
          lo2[k] = q1.x - q2.y * 0.5f; hi2[k] = q1.x + q2.y * 0.5f;
          vb[k] = (q1.y * q2.x) * q2.y;
          invp[k] = 0xFFFFFFFFu - (unsigned)p;
        } else {
          lo0[k] = lo1[k] = lo2[k] = 3e18f;
          hi0[k] = hi1[k] = hi2[k] = 3e18f;
          vb[k] = 0.f;
          invp[k] = 0u;
        }
      }

      float bv[MITEMS];
      int bo[MITEMS];
#pragma unroll
      for (int k = 0; k < MITEMS; ++k) { bv[k] = -1.0f; bo[k] = 0; }

      for (int pass = 0; pass < NOBJ / 8; ++pass) {
        if (pass) __syncthreads();
        float piou[8];
        unsigned pinv[8];
#pragma unroll
        for (int oo = 0; oo < 8; ++oo) { piou[oo] = 0.f; pinv[oo] = 0u; }
#pragma unroll
        for (int oo = 0; oo < 8; ++oo) {
          const int o = pass * 8 + oo;
          const float4 c0 = s_box[o][0];
          const float4 c1 = s_box[o][1];
#pragma unroll
          for (int k = 0; k < MITEMS; ++k) {
            const float d0 = fminf(c0.w, hi0[k]) - fmaxf(c0.x, lo0[k]);
            const float d1 = fminf(c1.x, hi1[k]) - fmaxf(c0.y, lo1[k]);
            const float d2 = fminf(c1.y, hi2[k]) - fmaxf(c0.z, lo2[k]);
            const float inter =
                (fmaxf(d0, 0.f) * fmaxf(d1, 0.f)) * fmaxf(d2, 0.f);
            const float un = (c1.z + vb[k]) - inter;
            const float iou = inter * __builtin_amdgcn_rcpf(un);
            if (iou > bv[k]) { bv[k] = iou; bo[k] = o; }  // first occurrence
            const bool win = iou > piou[oo];
            piou[oo] = win ? iou : piou[oo];
            pinv[oo] = win ? invp[k] : pinv[oo];
          }
        }
#pragma unroll
        for (int oo = 0; oo < 8; ++oo) {
          s_iou[oo][tid] = __float_as_uint(piou[oo]);
          s_pinv[oo][tid] = pinv[oo];
        }
        __syncthreads();
        const int obj8 = tid >> 5, j = tid & 31;
        unsigned long long m = 0ULL;
#pragma unroll
        for (int i = 0; i < 8; ++i) {
          const int col = j + 32 * i;
          m = umax64(m, ((unsigned long long)s_iou[obj8][col] << 32) |
                            s_pinv[obj8][col]);
        }
#pragma unroll
        for (int off = 1; off < 32; off <<= 1)
          m = umax64(m, __shfl_xor(m, off, 64));
        if (j == 0) {
          const int o = pass * 8 + obj8;
          if (o < n_obj) atomicMax(&prior_fo[(size_t)b * 64 + o], m);
        }
      }

#pragma unroll
      for (int k = 0; k < MITEMS; ++k) {
        const int p = pbase + k * 256 + tid;
        if (FULL || p < P)
          best_u8[(size_t)b * P + p] =
              (unsigned char)((unsigned)bo[k] | (bv[k] >= 0.5f ? 0x80u : 0u));
      }
    }
  }
  gridbar(cnt, gen);

  // ================= Phase B: loss + hist0 =================
  {
    unsigned* s_hist = (unsigned*)smem;                  // 16384
    float(*s_box)[6] = (float(*)[6])(smem + 16384);      // 1536
    int* s_lab = (int*)(smem + 17920);                   // 256
    unsigned* s_fo = (unsigned*)(smem + 18176);          // 256
    int* r_np = (int*)(smem + 18432);                    // 1024
    double* r_c = (double*)(smem + 19456);               // 2048
    double* r_l = (double*)(smem + 21504);               // 2048
    for (int job = bid; job < B * SUBS; job += NBLK) {
      const int b = job / SUBS;
      const int sub = job % SUBS;
      for (int i = tid; i < 4096; i += 256) s_hist[i] = 0u;
      for (int i = tid; i < n_obj * 6; i += 256)
        s_box[i / 6][i % 6] = boxes[(size_t)b * n_obj * 6 + i];
      for (int i = tid; i < n_obj; i += 256) {
        s_lab[i] = labels[(size_t)b * n_obj + i];
        s_fo[i] =
            0xFFFFFFFFu - (unsigned)(prior_fo[(size_t)b * 64 + i] & 0xFFFFFFFFull);
      }
      __syncthreads();

      unsigned fo_r[16];
      const bool small_obj = (n_obj <= 16);
      if (small_obj) {
#pragma unroll
        for (int o = 0; o < 16; ++o)
          fo_r[o] = (o < n_obj) ? s_fo[o] : 0xFFFFFFFEu;
      }

      int np_l = 0;
      double cf_l = 0.0, lc_l = 0.0;

      if (CC == 2 && (P & 1) == 0) {
        const int P2 = P >> 1;
        const int chunk = (P2 + SUBS - 1) / SUBS;
        const int start = sub * chunk;
        const int end = min(start + chunk, P2);
        for (int q = start + tid; q < end; q += 256) {
          const float4 sc = *(const float4*)(scores + ((size_t)b * P2 + q) * 4);
          const unsigned short bpp =
              *(const unsigned short*)(best_u8 + (size_t)b * P + 2 * q);
          float cn2[2];
#pragma unroll
          for (int e = 0; e < 2; ++e) {
            const int p = 2 * q + e;
            const unsigned bp = e ? (bpp >> 8) : (bpp & 0xFFu);
            int obj = bp & 0x7F;
            int posf = (int)(bp >> 7);
            if (small_obj) {
#pragma unroll
              for (int o = 0; o < 16; ++o)
                if (fo_r[o] == (unsigned)p) { obj = o; posf = 1; }  // last wins
            } else {
              for (int o = 0; o < n_obj; ++o)
                if (s_fo[o] == (unsigned)p) { obj = o; posf = 1; }
            }
            const int lab = posf ? s_lab[obj] : 0;
            const float sx = e ? sc.z : sc.x;
            const float sy = e ? sc.w : sc.y;
            const float mm = fmaxf(sx, sy);
            const float conf =
                (lab < 0) ? 0.f
                          : (mm + __logf(__expf(sx - mm) + __expf(sy - mm)) -
                             ((lab == 0) ? sx : sy));
            float cn = conf;
            if (lab > 0) {
              np_l++;
              cf_l += (double)conf;
              const float* pr = priors + (size_t)p * 6;
              const float* pl = locs + ((size_t)b * P + p) * 6;
              float ls = 0.f;
              for (int i = 0; i < 3; ++i) {
                const float c0 = (s_box[obj][i] + s_box[obj][i + 3]) * 0.5f;
                const float szb = s_box[obj][i + 3] - s_box[obj][i];
                const float g = (c0 - pr[i]) / (pr[i + 3] / 10.0f);
                const float g2 = logf(szb / pr[i + 3]) * 5.0f;
                ls += fabsf(pl[i] - g) + fabsf(pl[i + 3] - g2);
              }
              lc_l += (double)ls;
              cn = 0.f;
            }
            cn2[e] = cn;
            atomicAdd(&s_hist[__float_as_uint(cn) >> 20], 1u);
          }
          *(float2*)(conf_neg + (size_t)b * P + 2 * q) =
              make_float2(cn2[0], cn2[1]);
        }
      } else {
        const int chunk = (P + SUBS - 1) / SUBS;
        const int start = sub * chunk;
        const int end = min(start + chunk, P);
        for (int p = start + tid; p < end; p += 256) {
          const unsigned char bp = best_u8[(size_t)b * P + p];
          int obj = bp & 0x7F;
          int posf = bp >> 7;
          for (int o = 0; o < n_obj; ++o)
            if (s_fo[o] == (unsigned)p) { obj = o; posf = 1; }
          const int lab = posf ? s_lab[obj] : 0;
          const float* sp = scores + ((size_t)b * P + p) * CC;
          float m = sp[0];
          for (int c = 1; c < CC; ++c) m = fmaxf(m, sp[c]);
          float se = 0.f;
          for (int c = 0; c < CC; ++c) se += __expf(sp[c] - m);
          const float conf = (lab < 0) ? 0.f : (m + __logf(se) - sp[lab]);
          float cn = conf;
          if (lab > 0) {
            np_l++;
            cf_l += (double)conf;
            const float* pr = priors + (size_t)p * 6;
            const float* pl = locs + ((size_t)b * P + p) * 6;
            float ls = 0.f;
            for (int i = 0; i < 3; ++i) {
              const float c0 = (s_box[obj][i] + s_box[obj][i + 3]) * 0.5f;
              const float szb = s_box[obj][i + 3] - s_box[obj][i];
              const float g = (c0 - pr[i]) / (pr[i + 3] / 10.0f);
              const float g2 = logf(szb / pr[i + 3]) * 5.0f;
              ls += fabsf(pl[i] - g) + fabsf(pl[i + 3] - g2);
            }
            lc_l += (double)ls;
            cn = 0.f;
          }
          conf_neg[(size_t)b * P + p] = cn;
          atomicAdd(&s_hist[__float_as_uint(cn) >> 20], 1u);
        }
      }

      r_np[tid] = np_l;
      r_c[tid] = cf_l;
      r_l[tid] = lc_l;
      __syncthreads();
      for (int s = 128; s > 0; s >>= 1) {
        if (tid < s) {
          r_np[tid] += r_np[tid + s];
          r_c[tid] += r_c[tid + s];
          r_l[tid] += r_l[tid + s];
        }
        __syncthreads();
      }
      if (tid == 0 && r_np[0] > 0) {
        atomicAdd(&n_pos[b], r_np[0]);
        atomicAdd(&pconf[b], r_c[0]);
        atomicAdd(&ploc[b], r_l[0]);
      }
      for (int i = tid; i < 4096; i += 256)
        if (s_hist[i]) atomicAdd(&hist0[(size_t)b * 4096 + i], s_hist[i]);
      __syncthreads();
    }
  }
  gridbar(cnt, gen);

  // ================= Phase C: hist1 =================
  {
    unsigned* s_scan = (unsigned*)smem;            // 1024
    int* s_out = (int*)(smem + 1024);              // 16
    unsigned* s_hist = (unsigned*)(smem + 1040);   // 16384
    for (int job = bid; job < B * SUBS; job += NBLK) {
      const int b = job / SUBS;
      const int sub = job % SUBS;
      int K = 3 * n_pos[b];
      if (K > P) K = P;
      unsigned sel0;
      int rem0;
      block_select<4096>(hist0 + (size_t)b * 4096, K, s_scan, s_out, &sel0, &rem0);
      for (int i = tid; i < 4096; i += 256) s_hist[i] = 0u;
      __syncthreads();
      const float* row = conf_neg + (size_t)b * P;
      const int n4 = P >> 2;
      const int per = (n4 + SUBS - 1) / SUBS;
      const int s4 = sub * per, e4 = min(s4 + per, n4);
      for (int i = s4 + tid; i < e4; i += 256) {
        const float4 v = ((const float4*)row)[i];
        unsigned u;
        u = __float_as_uint(v.x); if ((u >> 20) == sel0) atomicAdd(&s_hist[(u >> 8) & 4095u], 1u);
        u = __float_as_uint(v.y); if ((u >> 20) == sel0) atomicAdd(&s_hist[(u >> 8) & 4095u], 1u);
        u = __float_as_uint(v.z); if ((u >> 20) == sel0) atomicAdd(&s_hist[(u >> 8) & 4095u], 1u);
        u = __float_as_uint(v.w); if ((u >> 20) == sel0) atomicAdd(&s_hist[(u >> 8) & 4095u], 1u);
      }
      if (sub == 0)
        for (int p = (n4 << 2) + tid; p < P; p += 256) {
          const unsigned u = __float_as_uint(row[p]);
          if ((u >> 20) == sel0) atomicAdd(&s_hist[(u >> 8) & 4095u], 1u);
        }
      __syncthreads();
      for (int i = tid; i < 4096; i += 256)
        if (s_hist[i]) atomicAdd(&hist1[(size_t)b * 4096 + i], s_hist[i]);
      __syncthreads();
    }
  }
  gridbar(cnt, gen);

  // ================= Phase D: sum =================
  {
    unsigned* s_scan = (unsigned*)smem;        // 1024
    int* s_out = (int*)(smem + 1024);          // 16
    double* red = (double*)(smem + 2048);      // 2048
    for (int job = bid; job < B * SUBS; job += NBLK) {
      const int b = job / SUBS;
      const int sub = job % SUBS;
      int K = 3 * n_pos[b];
      if (K > P) K = P;
      unsigned sel0, sel1;
      int rem0, rem1;
      block_select<4096>(hist0 + (size_t)b * 4096, K, s_scan, s_out, &sel0, &rem0);
      block_select<4096>(hist1 + (size_t)b * 4096, rem0, s_scan, s_out, &sel1, &rem1);
      const unsigned pref24 = (sel0 << 12) | sel1;
      const unsigned tb2 = (pref24 << 8) | 0xFFu;
      const float* row = conf_neg + (size_t)b * P;
      const int n4 = P >> 2;
      const int per = (n4 + SUBS - 1) / SUBS;
      const int s4 = sub * per, e4 = min(s4 + per, n4);
      double local = 0.0;
      for (int i = s4 + tid; i < e4; i += 256) {
        const float4 v = ((const float4*)row)[i];
        if (__float_as_uint(v.x) > tb2) local += (double)v.x;
        if (__float_as_uint(v.y) > tb2) local += (double)v.y;
        if (__float_as_uint(v.z) > tb2) local += (double)v.z;
        if (__float_as_uint(v.w) > tb2) local += (double)v.w;
      }
      if (sub == 0) {
        for (int p = (n4 << 2) + tid; p < P; p += 256) {
          const float v = row[p];
          if (__float_as_uint(v) > tb2) local += (double)v;
        }
        if (tid == 0 && rem1 > 0)
          local += (double)rem1 * (double)__uint_as_float((pref24 << 8) | 0x80u);
      }
      red[tid] = local;
      __syncthreads();
      for (int s = 128; s > 0; s >>= 1) {
        if (tid < s) red[tid] += red[tid + s];
        __syncthreads();
      }
      if (tid == 0 && red[0] != 0.0) atomicAdd(&phard[b], red[0]);
      __syncthreads();
    }
  }
  gridbar(cnt, gen);

  // ================= Finalize =================
  if (bid == 0 && tid == 0) {
    double tp = 0.0, cs = 0.0, ls = 0.0, hs = 0.0;
    for (int i = 0; i < B; ++i) {
      tp += (double)n_pos[i];
      cs += pconf[i];
      ls += ploc[i];
      hs += phard[i];
    }
    out[0] = (float)((hs + cs) / tp);
    out[1] = (float)(ls / (tp * 6.0));
  }
}

extern "C" void kernel_launch(void* const* d_in, const int* in_sizes, int n_in,
                              void* d_out, int out_size, void* d_ws, size_t ws_size,
                              hipStream_t stream) {
  const float* locs = (const float*)d_in[0];
  const float* scores = (const float*)d_in[1];
  const float* boxes = (const float*)d_in[2];
  const int* labels = (const int*)d_in[3];
  const float* priors = (const float*)d_in[4];

  const long long sz_locs = (long long)in_sizes[0];
  const long long sz_scores = (long long)in_sizes[1];
  const long long sz_priors = (long long)in_sizes[4];
  const int P = (int)(sz_priors / 6);
  const int B = (int)(sz_locs / sz_priors);
  const int n_obj = in_sizes[3] / B;
  const int C = (int)(sz_scores * 6 / sz_locs);

  char* ws = (char*)d_ws;
  size_t off = 0;
  double* pconf = (double*)(ws + off); off += (size_t)B * 8;
  double* ploc = (double*)(ws + off); off += (size_t)B * 8;
  double* phard = (double*)(ws + off); off += (size_t)B * 8;
  int* n_pos = (int*)(ws + off); off += ((size_t)B * 4 + 15) & ~(size_t)15;
  unsigned* cnt = (unsigned*)(ws + off); off += 8;
  unsigned* gen = (unsigned*)(ws + off); off += 8;
  unsigned long long* prior_fo = (unsigned long long*)(ws + off);
  off += (size_t)B * 64 * 8;
  unsigned* hist0 = (unsigned*)(ws + off); off += (size_t)B * 4096 * 4;
  unsigned* hist1 = (unsigned*)(ws + off); off += (size_t)B * 4096 * 4;
  const size_t zero_bytes = off;
  float* conf_neg = (float*)(ws + off); off += ((size_t)B * P * 4 + 15) & ~(size_t)15;
  unsigned char* best_u8 = (unsigned char*)(ws + off);
  off += ((size_t)B * P + 15) & ~(size_t)15;
  (void)ws_size;

  hipMemsetAsync(d_ws, 0, zero_bytes, stream);

  const bool full = (P % TILE) == 0;
  float* out = (float*)d_out;

#define LAUNCH(NO, CCV, FU)                                                  \
  mbl_mega<NO, CCV, FU><<<NBLK, 256, 0, stream>>>(                           \
      locs, scores, boxes, labels, priors, prior_fo, best_u8, conf_neg,      \
      hist0, hist1, n_pos, pconf, ploc, phard, cnt, gen, out, P, n_obj, B)

  if (C == 2) {
    if (n_obj <= 16) { if (full) LAUNCH(16, 2, true); else LAUNCH(16, 2, false); }
    else if (n_obj <= 32) { if (full) LAUNCH(32, 2, true); else LAUNCH(32, 2, false); }
    else { if (full) LAUNCH(64, 2, true); else LAUNCH(64, 2, false); }
  } else {
    if (n_obj <= 16) { if (full) LAUNCH(16, 3, true); else LAUNCH(16, 3, false); }
    else if (n_obj <= 32) { if (full) LAUNCH(32, 3, true); else LAUNCH(32, 3, false); }
    else { if (full) LAUNCH(64, 3, true); else LAUNCH(64, 3, false); }
  }
#undef LAUNCH
}

// Round 13
// 221.094 us; speedup vs baseline: 1.9428x; 1.9428x over previous
//
#include <hip/hip_runtime.h>
#include <math.h>

#define MITEMS 2
#define TILE 512  // 256 * MITEMS
#define LB 32     // blocks per batch for loss/hist/sum kernels
#define G3 16
#define CELLS 4096  // G3^3

// ---------------------------------------------------------------------------
// ws layout (memset region first):
//   double pconf[B], ploc[B], phard[B] ; int n_pos[B] ; u32 counter (+pad)
//   u64    prior_fo[B*64] ; u32 hist0[B][4096], hist1[B][4096]
//   u32    cellhist[4096], cellcnt[4096], maxhalf[4]
//   ---- end memset ----
//   u32    offs[4096] ; u32 mask32[B*4096]
//   float  conf_neg[B*P] ; u8 best_u8[B*P]
//   float4 sorted[P*2]  : {lo0,lo1,lo2,vb},{hi0,hi1,hi2,bits(cell<<17|origp)}
// ---------------------------------------------------------------------------

__device__ __forceinline__ unsigned long long umax64(unsigned long long a,
                                                     unsigned long long b) {
  return a > b ? a : b;
}

__device__ __forceinline__ int cell_of(float cx, float cy, float cz) {
  int ix = (int)(cx * G3); ix = min(max(ix, 0), G3 - 1);
  int iy = (int)(cy * G3); iy = min(max(iy, 0), G3 - 1);
  int iz = (int)(cz * G3); iz = min(max(iz, 0), G3 - 1);
  return (iz * G3 + iy) * G3 + ix;
}

// S1: per-cell prior histogram + max effective prior half-size per dim.
__global__ __launch_bounds__(256) void mbl_s1(const float* __restrict__ priors,
                                              unsigned* __restrict__ cellhist,
                                              unsigned* __restrict__ maxhalf,
                                              int P) {
  const int p = blockIdx.x * 256 + threadIdx.x;
  if (p >= P) return;
  const float2 q0 = *(const float2*)(priors + (size_t)p * 6);
  const float2 q1 = *(const float2*)(priors + (size_t)p * 6 + 2);
  const float2 q2 = *(const float2*)(priors + (size_t)p * 6 + 4);
  const float h0 = q1.y * 0.5f, h1 = q2.x * 0.5f, h2 = q2.y * 0.5f;
  // effective half = half + center clamp excess (conservative for mask test)
  const float e0 = h0 + fmaxf(q0.x - 1.f, 0.f) + fmaxf(-q0.x, 0.f);
  const float e1 = h1 + fmaxf(q0.y - 1.f, 0.f) + fmaxf(-q0.y, 0.f);
  const float e2 = h2 + fmaxf(q1.x - 1.f, 0.f) + fmaxf(-q1.x, 0.f);
  atomicMax(&maxhalf[0], __float_as_uint(fmaxf(e0, 0.f)));
  atomicMax(&maxhalf[1], __float_as_uint(fmaxf(e1, 0.f)));
  atomicMax(&maxhalf[2], __float_as_uint(fmaxf(e2, 0.f)));
  atomicAdd(&cellhist[cell_of(q0.x, q0.y, q1.x)], 1u);
}

// S2: block 0 = exclusive scan of cellhist -> offs; blocks 1..B = per-batch
// dilated cell/object masks + prior_fo seeds (iou=0, p=0).
__global__ __launch_bounds__(256) void mbl_s2(
    const float* __restrict__ boxes, const unsigned* __restrict__ cellhist,
    unsigned* __restrict__ offs, unsigned* __restrict__ mask32,
    unsigned long long* __restrict__ prior_fo,
    const unsigned* __restrict__ maxhalf, int n_obj) {
  const int t = threadIdx.x;
  if (blockIdx.x == 0) {
    __shared__ unsigned s_scan[256];
    unsigned v[16];
    unsigned s = 0;
#pragma unroll
    for (int i = 0; i < 16; ++i) { v[i] = cellhist[t * 16 + i]; s += v[i]; }
    unsigned incl = s;
    s_scan[t] = incl;
    __syncthreads();
    for (int off = 1; off < 256; off <<= 1) {
      const unsigned add = (t >= off) ? s_scan[t - off] : 0u;
      __syncthreads();
      incl += add;
      s_scan[t] = incl;
      __syncthreads();
    }
    unsigned base = incl - s;
#pragma unroll
    for (int i = 0; i < 16; ++i) { offs[t * 16 + i] = base; base += v[i]; }
  } else {
    const int b = blockIdx.x - 1;
    __shared__ float s_lo[64][3], s_hi[64][3];
    if (t < n_obj) {
      const float* q = boxes + ((size_t)b * n_obj + t) * 6;
      s_lo[t][0] = q[0]; s_lo[t][1] = q[1]; s_lo[t][2] = q[2];
      s_hi[t][0] = q[3]; s_hi[t][1] = q[4]; s_hi[t][2] = q[5];
      prior_fo[(size_t)b * 64 + t] = 0xFFFFFFFFull;  // seed: (iou 0, p 0)
    }
    __syncthreads();
    const float mh0 = __uint_as_float(maxhalf[0]);
    const float mh1 = __uint_as_float(maxhalf[1]);
    const float mh2 = __uint_as_float(maxhalf[2]);
    const int nm = min(n_obj, 32);
    const float inv = 1.0f / (float)G3;
    for (int c = t; c < CELLS; c += 256) {
      const int ix = c & (G3 - 1), iy = (c >> 4) & (G3 - 1), iz = c >> 8;
      const float clo0 = ix * inv, chi0 = (ix + 1) * inv;
      const float clo1 = iy * inv, chi1 = (iy + 1) * inv;
      const float clo2 = iz * inv, chi2 = (iz + 1) * inv;
      unsigned m = 0u;
      for (int o = 0; o < nm; ++o) {
        const bool ov = (s_lo[o][0] - mh0) <= chi0 && (s_hi[o][0] + mh0) >= clo0 &&
                        (s_lo[o][1] - mh1) <= chi1 && (s_hi[o][1] + mh1) >= clo1 &&
                        (s_lo[o][2] - mh2) <= chi2 && (s_hi[o][2] + mh2) >= clo2;
        m |= ov ? (1u << o) : 0u;
      }
      mask32[(size_t)b * CELLS + c] = m;
    }
  }
}

// S3: scatter priors into cell-sorted record array.
__global__ __launch_bounds__(256) void mbl_s3(const float* __restrict__ priors,
                                              const unsigned* __restrict__ offs,
                                              unsigned* __restrict__ cellcnt,
                                              float4* __restrict__ sorted, int P) {
  const int p = blockIdx.x * 256 + threadIdx.x;
  if (p >= P) return;
  const float2 q0 = *(const float2*)(priors + (size_t)p * 6);
  const float2 q1 = *(const float2*)(priors + (size_t)p * 6 + 2);
  const float2 q2 = *(const float2*)(priors + (size_t)p * 6 + 4);
  const float lo0 = q0.x - q1.y * 0.5f, hi0 = q0.x + q1.y * 0.5f;
  const float lo1 = q0.y - q2.x * 0.5f, hi1 = q0.y + q2.x * 0.5f;
  const float lo2 = q1.x - q2.y * 0.5f, hi2 = q1.x + q2.y * 0.5f;
  const float vb = (q1.y * q2.x) * q2.y;
  const int c = cell_of(q0.x, q0.y, q1.x);
  const unsigned slot = offs[c] + atomicAdd(&cellcnt[c], 1u);
  sorted[(size_t)slot * 2] = make_float4(lo0, lo1, lo2, vb);
  sorted[(size_t)slot * 2 + 1] =
      make_float4(hi0, hi1, hi2,
                  __uint_as_float(((unsigned)c << 17) | (unsigned)p));
}

// Match on sorted records; wave-uniform object skipping via cell masks.
template <int NOBJ, bool USEMASK>
__global__ __launch_bounds__(256) void mbl_match(
    const float* __restrict__ boxes, const float4* __restrict__ sorted,
    const unsigned* __restrict__ mask32, unsigned long long* __restrict__ prior_fo,
    unsigned char* __restrict__ best_u8, int P, int n_obj) {
  const int b = blockIdx.y;
  const int tid = threadIdx.x;
  __shared__ float4 s_box[NOBJ][2];
  __shared__ unsigned s_iou[8][264];
  __shared__ unsigned s_pinv[8][264];
  for (int i = tid; i < NOBJ; i += 256) {
    float4 v0, v1;
    if (i < n_obj) {
      const float* bx = boxes + ((size_t)b * n_obj + i) * 6;
      const float l0 = bx[0], l1 = bx[1], l2 = bx[2];
      const float h0 = bx[3], h1 = bx[4], h2 = bx[5];
      v0 = make_float4(l0, l1, l2, h0);
      v1 = make_float4(h1, h2, ((h0 - l0) * (h1 - l1)) * (h2 - l2), 0.f);
    } else {  // dummy object: iou 0 vs everything
      v0 = make_float4(3e18f, 3e18f, 3e18f, 1e18f);
      v1 = make_float4(1e18f, 1e18f, 0.f, 0.f);
    }
    s_box[i][0] = v0;
    s_box[i][1] = v1;
  }
  __syncthreads();

  const int pbase = blockIdx.x * TILE;
  float lo0[MITEMS], lo1[MITEMS], lo2[MITEMS], hi0[MITEMS], hi1[MITEMS],
      hi2[MITEMS], vb[MITEMS];
  unsigned invp[MITEMS], origp[MITEMS], lmk[MITEMS];
#pragma unroll
  for (int k = 0; k < MITEMS; ++k) {
    const int slot = pbase + k * 256 + tid;
    if (slot < P) {
      const float4 r0 = sorted[(size_t)slot * 2];
      const float4 r1 = sorted[(size_t)slot * 2 + 1];
      lo0[k] = r0.x; lo1[k] = r0.y; lo2[k] = r0.z; vb[k] = r0.w;
      hi0[k] = r1.x; hi1[k] = r1.y; hi2[k] = r1.z;
      const unsigned pkd = __float_as_uint(r1.w);
      const unsigned cell = pkd >> 17;
      origp[k] = pkd & 0x1FFFFu;
      invp[k] = 0xFFFFFFFFu - origp[k];
      lmk[k] = USEMASK ? mask32[(size_t)b * CELLS + cell] : 0xFFFFFFFFu;
    } else {  // dummy: iou 0, never wins
      lo0[k] = lo1[k] = lo2[k] = 3e18f;
      hi0[k] = hi1[k] = hi2[k] = 3e18f;
      vb[k] = 0.f;
      invp[k] = 0u;
      origp[k] = 0xFFFFFFFFu;
      lmk[k] = 0u;
    }
  }

  unsigned lm = lmk[0] | lmk[1];
#pragma unroll
  for (int off = 1; off < 64; off <<= 1) lm |= __shfl_xor(lm, off, 64);
  const unsigned umask =
      USEMASK ? __builtin_amdgcn_readfirstlane(lm) : 0xFFFFFFFFu;

  float bv[MITEMS];
  int bo[MITEMS];
#pragma unroll
  for (int k = 0; k < MITEMS; ++k) { bv[k] = 0.0f; bo[k] = 0; }  // zero default

  for (int pass = 0; pass < NOBJ / 8; ++pass) {
    if (pass) __syncthreads();
    float piou[8];
    unsigned pinv[8];
#pragma unroll
    for (int oo = 0; oo < 8; ++oo) { piou[oo] = 0.f; pinv[oo] = 0u; }
    const unsigned upass = (umask >> (pass * 8)) & 0xFFu;

#pragma unroll
    for (int oo = 0; oo < 8; ++oo) {
      if (upass & (1u << oo)) {  // wave-uniform scalar branch
        const int o = pass * 8 + oo;
        const float4 c0 = s_box[o][0];
        const float4 c1 = s_box[o][1];
#pragma unroll
        for (int k = 0; k < MITEMS; ++k) {
          const float d0 = fminf(c0.w, hi0[k]) - fmaxf(c0.x, lo0[k]);
          const float d1 = fminf(c1.x, hi1[k]) - fmaxf(c0.y, lo1[k]);
          const float d2 = fminf(c1.y, hi2[k]) - fmaxf(c0.z, lo2[k]);
          const float inter = (fmaxf(d0, 0.f) * fmaxf(d1, 0.f)) * fmaxf(d2, 0.f);
          const float un = (c1.z + vb[k]) - inter;
          const float iou = inter * __builtin_amdgcn_rcpf(un);
          if (iou > bv[k]) { bv[k] = iou; bo[k] = o; }  // strict: first occ.
          const bool win = iou > piou[oo];
          piou[oo] = win ? iou : piou[oo];
          pinv[oo] = win ? invp[k] : pinv[oo];
        }
      }
    }

    // exact per-object epilogue (always runs; skipped objects are (0,0))
#pragma unroll
    for (int oo = 0; oo < 8; ++oo) {
      s_iou[oo][tid] = __float_as_uint(piou[oo]);
      s_pinv[oo][tid] = pinv[oo];
    }
    __syncthreads();
    const int obj8 = tid >> 5, j = tid & 31;
    unsigned long long m = 0ULL;
#pragma unroll
    for (int i = 0; i < 8; ++i) {
      const int col = j + 32 * i;
      m = umax64(m, ((unsigned long long)s_iou[obj8][col] << 32) |
                        s_pinv[obj8][col]);
    }
#pragma unroll
    for (int off = 1; off < 32; off <<= 1)
      m = umax64(m, __shfl_xor(m, off, 64));
    if (j == 0) {
      const int o = pass * 8 + obj8;
      if (o < n_obj) atomicMax(&prior_fo[(size_t)b * 64 + o], m);
    }
  }

#pragma unroll
  for (int k = 0; k < MITEMS; ++k) {
    const int slot = pbase + k * 256 + tid;
    if (slot < P)
      best_u8[(size_t)b * P + origp[k]] =
          (unsigned char)((unsigned)bo[k] | (bv[k] >= 0.5f ? 0x80u : 0u));
  }
}

// Loss: override scan + CE + loc L1 + conf_neg + fused 12-bit hist0. (r11)
template <int CC>
__global__ __launch_bounds__(256) void mbl_loss(
    const float* __restrict__ locs, const float* __restrict__ scores,
    const float* __restrict__ boxes, const int* __restrict__ labels,
    const float* __restrict__ priors, const unsigned long long* __restrict__ prior_fo,
    const unsigned char* __restrict__ best_u8, float* __restrict__ conf_neg,
    unsigned* __restrict__ hist0, int* __restrict__ n_pos,
    double* __restrict__ pconf, double* __restrict__ ploc, int P, int n_obj,
    int C) {
  const int b = blockIdx.y;
  const int tid = threadIdx.x;
  __shared__ float s_box[64][6];
  __shared__ int s_lab[64];
  __shared__ unsigned s_fo[64];
  __shared__ unsigned s_hist[4096];
  for (int i = tid; i < 4096; i += 256) s_hist[i] = 0u;
  for (int i = tid; i < n_obj * 6; i += 256)
    s_box[i / 6][i % 6] = boxes[(size_t)b * n_obj * 6 + i];
  for (int i = tid; i < n_obj; i += 256) {
    s_lab[i] = labels[(size_t)b * n_obj + i];
    s_fo[i] = 0xFFFFFFFFu - (unsigned)(prior_fo[(size_t)b * 64 + i] & 0xFFFFFFFFull);
  }
  __syncthreads();

  unsigned fo_r[16];
  const bool small_obj = (n_obj <= 16);
  if (small_obj) {
#pragma unroll
    for (int o = 0; o < 16; ++o) fo_r[o] = (o < n_obj) ? s_fo[o] : 0xFFFFFFFEu;
  }

  int np_l = 0;
  double cf_l = 0.0, lc_l = 0.0;

  if (CC == 2 && (P & 1) == 0) {
    const int P2 = P >> 1;
    const int chunk = (P2 + (int)gridDim.x - 1) / (int)gridDim.x;
    const int start = blockIdx.x * chunk;
    const int end = min(start + chunk, P2);
    for (int q = start + tid; q < end; q += 256) {
      const float4 sc = *(const float4*)(scores + ((size_t)b * P2 + q) * 4);
      const unsigned short bpp =
          *(const unsigned short*)(best_u8 + (size_t)b * P + 2 * q);
      float cn2[2];
#pragma unroll
      for (int e = 0; e < 2; ++e) {
        const int p = 2 * q + e;
        const unsigned bp = e ? (bpp >> 8) : (bpp & 0xFFu);
        int obj = bp & 0x7F;
        int posf = (int)(bp >> 7);
        if (small_obj) {
#pragma unroll
          for (int o = 0; o < 16; ++o)
            if (fo_r[o] == (unsigned)p) { obj = o; posf = 1; }  // last wins
        } else {
          for (int o = 0; o < n_obj; ++o)
            if (s_fo[o] == (unsigned)p) { obj = o; posf = 1; }
        }
        const int lab = posf ? s_lab[obj] : 0;
        const float sx = e ? sc.z : sc.x;
        const float sy = e ? sc.w : sc.y;
        const float mm = fmaxf(sx, sy);
        const float conf =
            (lab < 0) ? 0.f
                      : (mm + __logf(__expf(sx - mm) + __expf(sy - mm)) -
                         ((lab == 0) ? sx : sy));
        float cn = conf;
        if (lab > 0) {
          np_l++;
          cf_l += (double)conf;
          const float* pr = priors + (size_t)p * 6;
          const float* pl = locs + ((size_t)b * P + p) * 6;
          float ls = 0.f;
          for (int i = 0; i < 3; ++i) {
            const float c0 = (s_box[obj][i] + s_box[obj][i + 3]) * 0.5f;
            const float szb = s_box[obj][i + 3] - s_box[obj][i];
            const float g = (c0 - pr[i]) / (pr[i + 3] / 10.0f);
            const float g2 = logf(szb / pr[i + 3]) * 5.0f;
            ls += fabsf(pl[i] - g) + fabsf(pl[i + 3] - g2);
          }
          lc_l += (double)ls;
          cn = 0.f;
        }
        cn2[e] = cn;
        atomicAdd(&s_hist[__float_as_uint(cn) >> 20], 1u);
      }
      *(float2*)(conf_neg + (size_t)b * P + 2 * q) = make_float2(cn2[0], cn2[1]);
    }
  } else {
    const int chunk = (P + (int)gridDim.x - 1) / (int)gridDim.x;
    const int start = blockIdx.x * chunk;
    const int end = min(start + chunk, P);
    for (int p = start + tid; p < end; p += 256) {
      const unsigned char bp = best_u8[(size_t)b * P + p];
      int obj = bp & 0x7F;
      int posf = bp >> 7;
      for (int o = 0; o < n_obj; ++o)
        if (s_fo[o] == (unsigned)p) { obj = o; posf = 1; }
      const int lab = posf ? s_lab[obj] : 0;
      const float* sp = scores + ((size_t)b * P + p) * C;
      float m = sp[0];
      for (int c = 1; c < C; ++c) m = fmaxf(m, sp[c]);
      float se = 0.f;
      for (int c = 0; c < C; ++c) se += __expf(sp[c] - m);
      const float conf = (lab < 0) ? 0.f : (m + __logf(se) - sp[lab]);
      float cn = conf;
      if (lab > 0) {
        np_l++;
        cf_l += (double)conf;
        const float* pr = priors + (size_t)p * 6;
        const float* pl = locs + ((size_t)b * P + p) * 6;
        float ls = 0.f;
        for (int i = 0; i < 3; ++i) {
          const float c0 = (s_box[obj][i] + s_box[obj][i + 3]) * 0.5f;
          const float szb = s_box[obj][i + 3] - s_box[obj][i];
          const float g = (c0 - pr[i]) / (pr[i + 3] / 10.0f);
          const float g2 = logf(szb / pr[i + 3]) * 5.0f;
          ls += fabsf(pl[i] - g) + fabsf(pl[i + 3] - g2);
        }
        lc_l += (double)ls;
        cn = 0.f;
      }
      conf_neg[(size_t)b * P + p] = cn;
      atomicAdd(&s_hist[__float_as_uint(cn) >> 20], 1u);
    }
  }

  __shared__ int r_np[256];
  __shared__ double r_c[256];
  __shared__ double r_l[256];
  r_np[tid] = np_l;
  r_c[tid] = cf_l;
  r_l[tid] = lc_l;
  __syncthreads();
  for (int s = 128; s > 0; s >>= 1) {
    if (tid < s) {
      r_np[tid] += r_np[tid + s];
      r_c[tid] += r_c[tid + s];
      r_l[tid] += r_l[tid + s];
    }
    __syncthreads();
  }
  if (tid == 0 && r_np[0] > 0) {
    atomicAdd(&n_pos[b], r_np[0]);
    atomicAdd(&pconf[b], r_c[0]);
    atomicAdd(&ploc[b], r_l[0]);
  }
  for (int i = tid; i < 4096; i += 256)
    if (s_hist[i]) atomicAdd(&hist0[(size_t)b * 4096 + i], s_hist[i]);
}

// Cooperative block-wide radix select over BINS bins (descending cumulative).
template <int BINS>
__device__ void block_select(const unsigned* __restrict__ h, int remk,
                             unsigned* s_scan, int* s_out, unsigned* sel,
                             int* remk_o) {
  constexpr int BPT = BINS / 256;
  const int t = threadIdx.x;
  if (t == 0) { s_out[0] = BINS - 1; s_out[1] = 0; }
  unsigned mb[BPT];
  unsigned s = 0;
#pragma unroll
  for (int i = 0; i < BPT; ++i) { mb[i] = h[t * BPT + i]; s += mb[i]; }
  unsigned incl = s;
  s_scan[t] = incl;
  __syncthreads();
  for (int off = 1; off < 256; off <<= 1) {
    const unsigned add = (t >= off) ? s_scan[t - off] : 0u;
    __syncthreads();
    incl += add;
    s_scan[t] = incl;
    __syncthreads();
  }
  const unsigned total = s_scan[255];
  const unsigned R = total - incl;
  if (remk > 0 && R < (unsigned)remk && R + s >= (unsigned)remk) {
    unsigned acc = R;
    int sel_i = t * BPT, rk = 0;
    bool done = false;
#pragma unroll
    for (int i = BPT - 1; i >= 0; --i) {
      if (!done && acc + mb[i] >= (unsigned)remk) {
        sel_i = t * BPT + i;
        rk = remk - (int)acc;
        done = true;
      }
      if (!done) acc += mb[i];
    }
    s_out[0] = sel_i;
    s_out[1] = rk;
  }
  __syncthreads();
  *sel = (unsigned)s_out[0];
  *remk_o = s_out[1];
  __syncthreads();
}

__global__ __launch_bounds__(256) void mbl_hist1(
    const float* __restrict__ conf_neg, const int* __restrict__ n_pos,
    const unsigned* __restrict__ hist0, unsigned* __restrict__ hist1, int P) {
  const int b = blockIdx.y;
  const int tid = threadIdx.x;
  __shared__ unsigned s_scan[256];
  __shared__ int s_out[2];
  __shared__ unsigned s_hist[4096];
  int K = 3 * n_pos[b];
  if (K > P) K = P;
  unsigned sel0;
  int rem0;
  block_select<4096>(hist0 + (size_t)b * 4096, K, s_scan, s_out, &sel0, &rem0);
  for (int i = tid; i < 4096; i += 256) s_hist[i] = 0u;
  __syncthreads();
  const float* row = conf_neg + (size_t)b * P;
  const int n4 = P >> 2;
  const int per = (n4 + (int)gridDim.x - 1) / (int)gridDim.x;
  const int s4 = blockIdx.x * per, e4 = min(s4 + per, n4);
  for (int i = s4 + tid; i < e4; i += 256) {
    const float4 v = ((const float4*)row)[i];
    unsigned u;
    u = __float_as_uint(v.x); if ((u >> 20) == sel0) atomicAdd(&s_hist[(u >> 8) & 4095u], 1u);
    u = __float_as_uint(v.y); if ((u >> 20) == sel0) atomicAdd(&s_hist[(u >> 8) & 4095u], 1u);
    u = __float_as_uint(v.z); if ((u >> 20) == sel0) atomicAdd(&s_hist[(u >> 8) & 4095u], 1u);
    u = __float_as_uint(v.w); if ((u >> 20) == sel0) atomicAdd(&s_hist[(u >> 8) & 4095u], 1u);
  }
  if (blockIdx.x == 0)
    for (int p = (n4 << 2) + tid; p < P; p += 256) {
      const unsigned u = __float_as_uint(row[p]);
      if ((u >> 20) == sel0) atomicAdd(&s_hist[(u >> 8) & 4095u], 1u);
    }
  __syncthreads();
  for (int i = tid; i < 4096; i += 256)
    if (s_hist[i]) atomicAdd(&hist1[(size_t)b * 4096 + i], s_hist[i]);
}

__global__ __launch_bounds__(256) void mbl_sum(
    const float* __restrict__ conf_neg, const int* __restrict__ n_pos,
    const unsigned* __restrict__ hist0, const unsigned* __restrict__ hist1,
    const double* __restrict__ pconf, const double* __restrict__ ploc,
    double* __restrict__ phard, unsigned* __restrict__ counter, int P, int B,
    float* __restrict__ out) {
  const int b = blockIdx.y;
  const int tid = threadIdx.x;
  __shared__ unsigned s_scan[256];
  __shared__ int s_out[2];
  int K = 3 * n_pos[b];
  if (K > P) K = P;
  unsigned sel0, sel1;
  int rem0, rem1;
  block_select<4096>(hist0 + (size_t)b * 4096, K, s_scan, s_out, &sel0, &rem0);
  block_select<4096>(hist1 + (size_t)b * 4096, rem0, s_scan, s_out, &sel1, &rem1);
  const unsigned pref24 = (sel0 << 12) | sel1;
  const unsigned tb = (pref24 << 8) | 0xFFu;
  const float* row = conf_neg + (size_t)b * P;
  const int n4 = P >> 2;
  const int per = (n4 + (int)gridDim.x - 1) / (int)gridDim.x;
  const int s4 = blockIdx.x * per, e4 = min(s4 + per, n4);
  double local = 0.0;
  for (int i = s4 + tid; i < e4; i += 256) {
    const float4 v = ((const float4*)row)[i];
    if (__float_as_uint(v.x) > tb) local += (double)v.x;
    if (__float_as_uint(v.y) > tb) local += (double)v.y;
    if (__float_as_uint(v.z) > tb) local += (double)v.z;
    if (__float_as_uint(v.w) > tb) local += (double)v.w;
  }
  if (blockIdx.x == 0) {
    for (int p = (n4 << 2) + tid; p < P; p += 256) {
      const float v = row[p];
      if (__float_as_uint(v) > tb) local += (double)v;
    }
    if (tid == 0 && rem1 > 0)
      local += (double)rem1 * (double)__uint_as_float((pref24 << 8) | 0x80u);
  }
  __shared__ double red[256];
  red[tid] = local;
  __syncthreads();
  for (int s = 128; s > 0; s >>= 1) {
    if (tid < s) red[tid] += red[tid + s];
    __syncthreads();
  }
  if (tid == 0) {
    if (red[0] != 0.0) atomicAdd(&phard[b], red[0]);
    __threadfence();
    const unsigned done = atomicAdd(counter, 1u);
    if (done == gridDim.x * gridDim.y - 1) {
      double tp = 0.0, cs = 0.0, ls = 0.0, hs = 0.0;
      for (int i = 0; i < B; ++i) {
        tp += (double)n_pos[i];
        cs += pconf[i];
        ls += ploc[i];
        hs += atomicAdd(&phard[i], 0.0);
      }
      out[0] = (float)((hs + cs) / tp);
      out[1] = (float)(ls / (tp * 6.0));
    }
  }
}

extern "C" void kernel_launch(void* const* d_in, const int* in_sizes, int n_in,
                              void* d_out, int out_size, void* d_ws, size_t ws_size,
                              hipStream_t stream) {
  const float* locs = (const float*)d_in[0];
  const float* scores = (const float*)d_in[1];
  const float* boxes = (const float*)d_in[2];
  const int* labels = (const int*)d_in[3];
  const float* priors = (const float*)d_in[4];

  const long long sz_locs = (long long)in_sizes[0];
  const long long sz_scores = (long long)in_sizes[1];
  const long long sz_priors = (long long)in_sizes[4];
  const int P = (int)(sz_priors / 6);
  const int B = (int)(sz_locs / sz_priors);
  const int n_obj = in_sizes[3] / B;
  const int C = (int)(sz_scores * 6 / sz_locs);

  char* ws = (char*)d_ws;
  size_t off = 0;
  double* pconf = (double*)(ws + off); off += (size_t)B * 8;
  double* ploc = (double*)(ws + off); off += (size_t)B * 8;
  double* phard = (double*)(ws + off); off += (size_t)B * 8;
  int* n_pos = (int*)(ws + off); off += ((size_t)B * 4 + 15) & ~(size_t)15;
  unsigned* counter = (unsigned*)(ws + off); off += 16;
  unsigned long long* prior_fo = (unsigned long long*)(ws + off);
  off += (size_t)B * 64 * 8;
  unsigned* hist0 = (unsigned*)(ws + off); off += (size_t)B * 4096 * 4;
  unsigned* hist1 = (unsigned*)(ws + off); off += (size_t)B * 4096 * 4;
  unsigned* cellhist = (unsigned*)(ws + off); off += (size_t)CELLS * 4;
  unsigned* cellcnt = (unsigned*)(ws + off); off += (size_t)CELLS * 4;
  unsigned* maxhalf = (unsigned*)(ws + off); off += 16;
  const size_t zero_bytes = off;
  unsigned* offs = (unsigned*)(ws + off); off += (size_t)CELLS * 4;
  unsigned* mask32 = (unsigned*)(ws + off); off += (size_t)B * CELLS * 4;
  float* conf_neg = (float*)(ws + off); off += ((size_t)B * P * 4 + 15) & ~(size_t)15;
  unsigned char* best_u8 = (unsigned char*)(ws + off);
  off += ((size_t)B * P + 15) & ~(size_t)15;
  off = (off + 15) & ~(size_t)15;
  float4* sorted = (float4*)(ws + off); off += (size_t)P * 2 * 16;
  (void)ws_size;

  hipMemsetAsync(d_ws, 0, zero_bytes, stream);

  const int pblk = (P + 255) / 256;
  mbl_s1<<<pblk, 256, 0, stream>>>(priors, cellhist, maxhalf, P);
  mbl_s2<<<1 + B, 256, 0, stream>>>(boxes, cellhist, offs, mask32, prior_fo,
                                    maxhalf, n_obj);
  mbl_s3<<<pblk, 256, 0, stream>>>(priors, offs, cellcnt, sorted, P);

  const int nblk = (P + TILE - 1) / TILE;
  const dim3 mgrid(nblk, B);
  if (n_obj <= 16) {
    mbl_match<16, true><<<mgrid, 256, 0, stream>>>(boxes, sorted, mask32,
                                                   prior_fo, best_u8, P, n_obj);
  } else if (n_obj <= 32) {
    mbl_match<32, true><<<mgrid, 256, 0, stream>>>(boxes, sorted, mask32,
                                                   prior_fo, best_u8, P, n_obj);
  } else {
    mbl_match<64, false><<<mgrid, 256, 0, stream>>>(boxes, sorted, mask32,
                                                    prior_fo, best_u8, P, n_obj);
  }

  const dim3 lgrid(LB, B);
  if (C == 2)
    mbl_loss<2><<<lgrid, 256, 0, stream>>>(locs, scores, boxes, labels, priors,
                                           prior_fo, best_u8, conf_neg, hist0, n_pos,
                                           pconf, ploc, P, n_obj, C);
  else
    mbl_loss<0><<<lgrid, 256, 0, stream>>>(locs, scores, boxes, labels, priors,
                                           prior_fo, best_u8, conf_neg, hist0, n_pos,
                                           pconf, ploc, P, n_obj, C);

  mbl_hist1<<<lgrid, 256, 0, stream>>>(conf_neg, n_pos, hist0, hist1, P);
  mbl_sum<<<lgrid, 256, 0, stream>>>(conf_neg, n_pos, hist0, hist1, pconf, ploc,
                                     phard, counter, P, B, (float*)d_out);
}

// Round 14
// 170.782 us; speedup vs baseline: 2.5152x; 1.2946x over previous
//
#include <hip/hip_runtime.h>
#include <math.h>

#define MITEMS 2
#define TILE 512  // 256 * MITEMS
#define LB 32     // blocks per batch for loss/hist/sum kernels
#define G3 16
#define CELLS 4096  // G3^3

// ---------------------------------------------------------------------------
// ws layout (memset region first):
//   double pconf[B], ploc[B], phard[B] ; int n_pos[B] ; u32 counter (+pad)
//   u64    prior_fo[B*64] ; u32 hist0[B][4096], hist1[B][4096]
//   u32    cellhist[4096], cellcnt[4096], maxhalf[4]
//   ---- end memset ----
//   u32    offs[4096] ; u32 mask32[B*4096]
//   float  conf_neg[B*P] ; u8 best_u8[B*P]
//   float4 sorted[P*2]  : {lo0,lo1,lo2,vb},{hi0,hi1,hi2,bits(cell<<17|origp)}
// ---------------------------------------------------------------------------

__device__ __forceinline__ unsigned long long umax64(unsigned long long a,
                                                     unsigned long long b) {
  return a > b ? a : b;
}

__device__ __forceinline__ int cell_of(float cx, float cy, float cz) {
  int ix = (int)(cx * G3); ix = min(max(ix, 0), G3 - 1);
  int iy = (int)(cy * G3); iy = min(max(iy, 0), G3 - 1);
  int iz = (int)(cz * G3); iz = min(max(iz, 0), G3 - 1);
  return (iz * G3 + iy) * G3 + ix;
}

// S1: per-cell prior histogram + max effective prior half-size per dim.
// maxhalf via block-reduce + ONE atomic triple per block (G12: no same-
// address atomic storms — r13's per-thread atomicMax was 70us of the 74).
__global__ __launch_bounds__(256) void mbl_s1(const float* __restrict__ priors,
                                              unsigned* __restrict__ cellhist,
                                              unsigned* __restrict__ maxhalf,
                                              int P) {
  const int p = blockIdx.x * 256 + threadIdx.x;
  float e0 = 0.f, e1 = 0.f, e2 = 0.f;
  if (p < P) {
    const float2 q0 = *(const float2*)(priors + (size_t)p * 6);
    const float2 q1 = *(const float2*)(priors + (size_t)p * 6 + 2);
    const float2 q2 = *(const float2*)(priors + (size_t)p * 6 + 4);
    const float h0 = q1.y * 0.5f, h1 = q2.x * 0.5f, h2 = q2.y * 0.5f;
    // effective half = half + center clamp excess (conservative for mask test)
    e0 = fmaxf(h0 + fmaxf(q0.x - 1.f, 0.f) + fmaxf(-q0.x, 0.f), 0.f);
    e1 = fmaxf(h1 + fmaxf(q0.y - 1.f, 0.f) + fmaxf(-q0.y, 0.f), 0.f);
    e2 = fmaxf(h2 + fmaxf(q1.x - 1.f, 0.f) + fmaxf(-q1.x, 0.f), 0.f);
    atomicAdd(&cellhist[cell_of(q0.x, q0.y, q1.x)], 1u);
  }
  // wave butterfly max (values >= 0 -> uint-order == float-order)
#pragma unroll
  for (int off = 1; off < 64; off <<= 1) {
    e0 = fmaxf(e0, __shfl_xor(e0, off, 64));
    e1 = fmaxf(e1, __shfl_xor(e1, off, 64));
    e2 = fmaxf(e2, __shfl_xor(e2, off, 64));
  }
  __shared__ float s0[4], s1v[4], s2v[4];
  const int wave = threadIdx.x >> 6, lane = threadIdx.x & 63;
  if (lane == 0) { s0[wave] = e0; s1v[wave] = e1; s2v[wave] = e2; }
  __syncthreads();
  if (threadIdx.x == 0) {
    float m0 = s0[0], m1 = s1v[0], m2 = s2v[0];
    for (int w = 1; w < 4; ++w) {
      m0 = fmaxf(m0, s0[w]);
      m1 = fmaxf(m1, s1v[w]);
      m2 = fmaxf(m2, s2v[w]);
    }
    atomicMax(&maxhalf[0], __float_as_uint(m0));
    atomicMax(&maxhalf[1], __float_as_uint(m1));
    atomicMax(&maxhalf[2], __float_as_uint(m2));
  }
}

// S2: block 0 = exclusive scan of cellhist -> offs; blocks 1..B = per-batch
// dilated cell/object masks + prior_fo seeds (iou=0, p=0).
__global__ __launch_bounds__(256) void mbl_s2(
    const float* __restrict__ boxes, const unsigned* __restrict__ cellhist,
    unsigned* __restrict__ offs, unsigned* __restrict__ mask32,
    unsigned long long* __restrict__ prior_fo,
    const unsigned* __restrict__ maxhalf, int n_obj) {
  const int t = threadIdx.x;
  if (blockIdx.x == 0) {
    __shared__ unsigned s_scan[256];
    unsigned v[16];
    unsigned s = 0;
#pragma unroll
    for (int i = 0; i < 16; ++i) { v[i] = cellhist[t * 16 + i]; s += v[i]; }
    unsigned incl = s;
    s_scan[t] = incl;
    __syncthreads();
    for (int off = 1; off < 256; off <<= 1) {
      const unsigned add = (t >= off) ? s_scan[t - off] : 0u;
      __syncthreads();
      incl += add;
      s_scan[t] = incl;
      __syncthreads();
    }
    unsigned base = incl - s;
#pragma unroll
    for (int i = 0; i < 16; ++i) { offs[t * 16 + i] = base; base += v[i]; }
  } else {
    const int b = blockIdx.x - 1;
    __shared__ float s_lo[64][3], s_hi[64][3];
    if (t < n_obj) {
      const float* q = boxes + ((size_t)b * n_obj + t) * 6;
      s_lo[t][0] = q[0]; s_lo[t][1] = q[1]; s_lo[t][2] = q[2];
      s_hi[t][0] = q[3]; s_hi[t][1] = q[4]; s_hi[t][2] = q[5];
      prior_fo[(size_t)b * 64 + t] = 0xFFFFFFFFull;  // seed: (iou 0, p 0)
    }
    __syncthreads();
    const float mh0 = __uint_as_float(maxhalf[0]);
    const float mh1 = __uint_as_float(maxhalf[1]);
    const float mh2 = __uint_as_float(maxhalf[2]);
    const int nm = min(n_obj, 32);
    const float inv = 1.0f / (float)G3;
    for (int c = t; c < CELLS; c += 256) {
      const int ix = c & (G3 - 1), iy = (c >> 4) & (G3 - 1), iz = c >> 8;
      const float clo0 = ix * inv, chi0 = (ix + 1) * inv;
      const float clo1 = iy * inv, chi1 = (iy + 1) * inv;
      const float clo2 = iz * inv, chi2 = (iz + 1) * inv;
      unsigned m = 0u;
      for (int o = 0; o < nm; ++o) {
        const bool ov = (s_lo[o][0] - mh0) <= chi0 && (s_hi[o][0] + mh0) >= clo0 &&
                        (s_lo[o][1] - mh1) <= chi1 && (s_hi[o][1] + mh1) >= clo1 &&
                        (s_lo[o][2] - mh2) <= chi2 && (s_hi[o][2] + mh2) >= clo2;
        m |= ov ? (1u << o) : 0u;
      }
      mask32[(size_t)b * CELLS + c] = m;
    }
  }
}

// S3: scatter priors into cell-sorted record array.
__global__ __launch_bounds__(256) void mbl_s3(const float* __restrict__ priors,
                                              const unsigned* __restrict__ offs,
                                              unsigned* __restrict__ cellcnt,
                                              float4* __restrict__ sorted, int P) {
  const int p = blockIdx.x * 256 + threadIdx.x;
  if (p >= P) return;
  const float2 q0 = *(const float2*)(priors + (size_t)p * 6);
  const float2 q1 = *(const float2*)(priors + (size_t)p * 6 + 2);
  const float2 q2 = *(const float2*)(priors + (size_t)p * 6 + 4);
  const float lo0 = q0.x - q1.y * 0.5f, hi0 = q0.x + q1.y * 0.5f;
  const float lo1 = q0.y - q2.x * 0.5f, hi1 = q0.y + q2.x * 0.5f;
  const float lo2 = q1.x - q2.y * 0.5f, hi2 = q1.x + q2.y * 0.5f;
  const float vb = (q1.y * q2.x) * q2.y;
  const int c = cell_of(q0.x, q0.y, q1.x);
  const unsigned slot = offs[c] + atomicAdd(&cellcnt[c], 1u);
  sorted[(size_t)slot * 2] = make_float4(lo0, lo1, lo2, vb);
  sorted[(size_t)slot * 2 + 1] =
      make_float4(hi0, hi1, hi2,
                  __uint_as_float(((unsigned)c << 17) | (unsigned)p));
}

// Match on sorted records; wave-uniform object skipping via cell masks.
template <int NOBJ, bool USEMASK>
__global__ __launch_bounds__(256) void mbl_match(
    const float* __restrict__ boxes, const float4* __restrict__ sorted,
    const unsigned* __restrict__ mask32, unsigned long long* __restrict__ prior_fo,
    unsigned char* __restrict__ best_u8, int P, int n_obj) {
  const int b = blockIdx.y;
  const int tid = threadIdx.x;
  __shared__ float4 s_box[NOBJ][2];
  __shared__ unsigned s_iou[8][264];
  __shared__ unsigned s_pinv[8][264];
  for (int i = tid; i < NOBJ; i += 256) {
    float4 v0, v1;
    if (i < n_obj) {
      const float* bx = boxes + ((size_t)b * n_obj + i) * 6;
      const float l0 = bx[0], l1 = bx[1], l2 = bx[2];
      const float h0 = bx[3], h1 = bx[4], h2 = bx[5];
      v0 = make_float4(l0, l1, l2, h0);
      v1 = make_float4(h1, h2, ((h0 - l0) * (h1 - l1)) * (h2 - l2), 0.f);
    } else {  // dummy object: iou 0 vs everything
      v0 = make_float4(3e18f, 3e18f, 3e18f, 1e18f);
      v1 = make_float4(1e18f, 1e18f, 0.f, 0.f);
    }
    s_box[i][0] = v0;
    s_box[i][1] = v1;
  }
  __syncthreads();

  const int pbase = blockIdx.x * TILE;
  float lo0[MITEMS], lo1[MITEMS], lo2[MITEMS], hi0[MITEMS], hi1[MITEMS],
      hi2[MITEMS], vb[MITEMS];
  unsigned invp[MITEMS], origp[MITEMS], lmk[MITEMS];
#pragma unroll
  for (int k = 0; k < MITEMS; ++k) {
    const int slot = pbase + k * 256 + tid;
    if (slot < P) {
      const float4 r0 = sorted[(size_t)slot * 2];
      const float4 r1 = sorted[(size_t)slot * 2 + 1];
      lo0[k] = r0.x; lo1[k] = r0.y; lo2[k] = r0.z; vb[k] = r0.w;
      hi0[k] = r1.x; hi1[k] = r1.y; hi2[k] = r1.z;
      const unsigned pkd = __float_as_uint(r1.w);
      const unsigned cell = pkd >> 17;
      origp[k] = pkd & 0x1FFFFu;
      invp[k] = 0xFFFFFFFFu - origp[k];
      lmk[k] = USEMASK ? mask32[(size_t)b * CELLS + cell] : 0xFFFFFFFFu;
    } else {  // dummy: iou 0, never wins
      lo0[k] = lo1[k] = lo2[k] = 3e18f;
      hi0[k] = hi1[k] = hi2[k] = 3e18f;
      vb[k] = 0.f;
      invp[k] = 0u;
      origp[k] = 0xFFFFFFFFu;
      lmk[k] = 0u;
    }
  }

  unsigned lm = lmk[0] | lmk[1];
#pragma unroll
  for (int off = 1; off < 64; off <<= 1) lm |= __shfl_xor(lm, off, 64);
  const unsigned umask =
      USEMASK ? __builtin_amdgcn_readfirstlane(lm) : 0xFFFFFFFFu;

  float bv[MITEMS];
  int bo[MITEMS];
#pragma unroll
  for (int k = 0; k < MITEMS; ++k) { bv[k] = 0.0f; bo[k] = 0; }  // zero default

  for (int pass = 0; pass < NOBJ / 8; ++pass) {
    if (pass) __syncthreads();
    float piou[8];
    unsigned pinv[8];
#pragma unroll
    for (int oo = 0; oo < 8; ++oo) { piou[oo] = 0.f; pinv[oo] = 0u; }
    const unsigned upass = (umask >> (pass * 8)) & 0xFFu;

#pragma unroll
    for (int oo = 0; oo < 8; ++oo) {
      if (upass & (1u << oo)) {  // wave-uniform scalar branch
        const int o = pass * 8 + oo;
        const float4 c0 = s_box[o][0];
        const float4 c1 = s_box[o][1];
#pragma unroll
        for (int k = 0; k < MITEMS; ++k) {
          const float d0 = fminf(c0.w, hi0[k]) - fmaxf(c0.x, lo0[k]);
          const float d1 = fminf(c1.x, hi1[k]) - fmaxf(c0.y, lo1[k]);
          const float d2 = fminf(c1.y, hi2[k]) - fmaxf(c0.z, lo2[k]);
          const float inter = (fmaxf(d0, 0.f) * fmaxf(d1, 0.f)) * fmaxf(d2, 0.f);
          const float un = (c1.z + vb[k]) - inter;
          const float iou = inter * __builtin_amdgcn_rcpf(un);
          if (iou > bv[k]) { bv[k] = iou; bo[k] = o; }  // strict: first occ.
          const bool win = iou > piou[oo];
          piou[oo] = win ? iou : piou[oo];
          pinv[oo] = win ? invp[k] : pinv[oo];
        }
      }
    }

    // exact per-object epilogue (always runs; skipped objects are (0,0))
#pragma unroll
    for (int oo = 0; oo < 8; ++oo) {
      s_iou[oo][tid] = __float_as_uint(piou[oo]);
      s_pinv[oo][tid] = pinv[oo];
    }
    __syncthreads();
    const int obj8 = tid >> 5, j = tid & 31;
    unsigned long long m = 0ULL;
#pragma unroll
    for (int i = 0; i < 8; ++i) {
      const int col = j + 32 * i;
      m = umax64(m, ((unsigned long long)s_iou[obj8][col] << 32) |
                        s_pinv[obj8][col]);
    }
#pragma unroll
    for (int off = 1; off < 32; off <<= 1)
      m = umax64(m, __shfl_xor(m, off, 64));
    if (j == 0) {
      const int o = pass * 8 + obj8;
      if (o < n_obj) atomicMax(&prior_fo[(size_t)b * 64 + o], m);
    }
  }

#pragma unroll
  for (int k = 0; k < MITEMS; ++k) {
    const int slot = pbase + k * 256 + tid;
    if (slot < P)
      best_u8[(size_t)b * P + origp[k]] =
          (unsigned char)((unsigned)bo[k] | (bv[k] >= 0.5f ? 0x80u : 0u));
  }
}

// Loss: override scan + CE + loc L1 + conf_neg + fused 12-bit hist0. (r11)
template <int CC>
__global__ __launch_bounds__(256) void mbl_loss(
    const float* __restrict__ locs, const float* __restrict__ scores,
    const float* __restrict__ boxes, const int* __restrict__ labels,
    const float* __restrict__ priors, const unsigned long long* __restrict__ prior_fo,
    const unsigned char* __restrict__ best_u8, float* __restrict__ conf_neg,
    unsigned* __restrict__ hist0, int* __restrict__ n_pos,
    double* __restrict__ pconf, double* __restrict__ ploc, int P, int n_obj,
    int C) {
  const int b = blockIdx.y;
  const int tid = threadIdx.x;
  __shared__ float s_box[64][6];
  __shared__ int s_lab[64];
  __shared__ unsigned s_fo[64];
  __shared__ unsigned s_hist[4096];
  for (int i = tid; i < 4096; i += 256) s_hist[i] = 0u;
  for (int i = tid; i < n_obj * 6; i += 256)
    s_box[i / 6][i % 6] = boxes[(size_t)b * n_obj * 6 + i];
  for (int i = tid; i < n_obj; i += 256) {
    s_lab[i] = labels[(size_t)b * n_obj + i];
    s_fo[i] = 0xFFFFFFFFu - (unsigned)(prior_fo[(size_t)b * 64 + i] & 0xFFFFFFFFull);
  }
  __syncthreads();

  unsigned fo_r[16];
  const bool small_obj = (n_obj <= 16);
  if (small_obj) {
#pragma unroll
    for (int o = 0; o < 16; ++o) fo_r[o] = (o < n_obj) ? s_fo[o] : 0xFFFFFFFEu;
  }

  int np_l = 0;
  double cf_l = 0.0, lc_l = 0.0;

  if (CC == 2 && (P & 1) == 0) {
    const int P2 = P >> 1;
    const int chunk = (P2 + (int)gridDim.x - 1) / (int)gridDim.x;
    const int start = blockIdx.x * chunk;
    const int end = min(start + chunk, P2);
    for (int q = start + tid; q < end; q += 256) {
      const float4 sc = *(const float4*)(scores + ((size_t)b * P2 + q) * 4);
      const unsigned short bpp =
          *(const unsigned short*)(best_u8 + (size_t)b * P + 2 * q);
      float cn2[2];
#pragma unroll
      for (int e = 0; e < 2; ++e) {
        const int p = 2 * q + e;
        const unsigned bp = e ? (bpp >> 8) : (bpp & 0xFFu);
        int obj = bp & 0x7F;
        int posf = (int)(bp >> 7);
        if (small_obj) {
#pragma unroll
          for (int o = 0; o < 16; ++o)
            if (fo_r[o] == (unsigned)p) { obj = o; posf = 1; }  // last wins
        } else {
          for (int o = 0; o < n_obj; ++o)
            if (s_fo[o] == (unsigned)p) { obj = o; posf = 1; }
        }
        const int lab = posf ? s_lab[obj] : 0;
        const float sx = e ? sc.z : sc.x;
        const float sy = e ? sc.w : sc.y;
        const float mm = fmaxf(sx, sy);
        const float conf =
            (lab < 0) ? 0.f
                      : (mm + __logf(__expf(sx - mm) + __expf(sy - mm)) -
                         ((lab == 0) ? sx : sy));
        float cn = conf;
        if (lab > 0) {
          np_l++;
          cf_l += (double)conf;
          const float* pr = priors + (size_t)p * 6;
          const float* pl = locs + ((size_t)b * P + p) * 6;
          float ls = 0.f;
          for (int i = 0; i < 3; ++i) {
            const float c0 = (s_box[obj][i] + s_box[obj][i + 3]) * 0.5f;
            const float szb = s_box[obj][i + 3] - s_box[obj][i];
            const float g = (c0 - pr[i]) / (pr[i + 3] / 10.0f);
            const float g2 = logf(szb / pr[i + 3]) * 5.0f;
            ls += fabsf(pl[i] - g) + fabsf(pl[i + 3] - g2);
          }
          lc_l += (double)ls;
          cn = 0.f;
        }
        cn2[e] = cn;
        atomicAdd(&s_hist[__float_as_uint(cn) >> 20], 1u);
      }
      *(float2*)(conf_neg + (size_t)b * P + 2 * q) = make_float2(cn2[0], cn2[1]);
    }
  } else {
    const int chunk = (P + (int)gridDim.x - 1) / (int)gridDim.x;
    const int start = blockIdx.x * chunk;
    const int end = min(start + chunk, P);
    for (int p = start + tid; p < end; p += 256) {
      const unsigned char bp = best_u8[(size_t)b * P + p];
      int obj = bp & 0x7F;
      int posf = bp >> 7;
      for (int o = 0; o < n_obj; ++o)
        if (s_fo[o] == (unsigned)p) { obj = o; posf = 1; }
      const int lab = posf ? s_lab[obj] : 0;
      const float* sp = scores + ((size_t)b * P + p) * C;
      float m = sp[0];
      for (int c = 1; c < C; ++c) m = fmaxf(m, sp[c]);
      float se = 0.f;
      for (int c = 0; c < C; ++c) se += __expf(sp[c] - m);
      const float conf = (lab < 0) ? 0.f : (m + __logf(se) - sp[lab]);
      float cn = conf;
      if (lab > 0) {
        np_l++;
        cf_l += (double)conf;
        const float* pr = priors + (size_t)p * 6;
        const float* pl = locs + ((size_t)b * P + p) * 6;
        float ls = 0.f;
        for (int i = 0; i < 3; ++i) {
          const float c0 = (s_box[obj][i] + s_box[obj][i + 3]) * 0.5f;
          const float szb = s_box[obj][i + 3] - s_box[obj][i];
          const float g = (c0 - pr[i]) / (pr[i + 3] / 10.0f);
          const float g2 = logf(szb / pr[i + 3]) * 5.0f;
          ls += fabsf(pl[i] - g) + fabsf(pl[i + 3] - g2);
        }
        lc_l += (double)ls;
        cn = 0.f;
      }
      conf_neg[(size_t)b * P + p] = cn;
      atomicAdd(&s_hist[__float_as_uint(cn) >> 20], 1u);
    }
  }

  __shared__ int r_np[256];
  __shared__ double r_c[256];
  __shared__ double r_l[256];
  r_np[tid] = np_l;
  r_c[tid] = cf_l;
  r_l[tid] = lc_l;
  __syncthreads();
  for (int s = 128; s > 0; s >>= 1) {
    if (tid < s) {
      r_np[tid] += r_np[tid + s];
      r_c[tid] += r_c[tid + s];
      r_l[tid] += r_l[tid + s];
    }
    __syncthreads();
  }
  if (tid == 0 && r_np[0] > 0) {
    atomicAdd(&n_pos[b], r_np[0]);
    atomicAdd(&pconf[b], r_c[0]);
    atomicAdd(&ploc[b], r_l[0]);
  }
  for (int i = tid; i < 4096; i += 256)
    if (s_hist[i]) atomicAdd(&hist0[(size_t)b * 4096 + i], s_hist[i]);
}

// Cooperative block-wide radix select over BINS bins (descending cumulative).
template <int BINS>
__device__ void block_select(const unsigned* __restrict__ h, int remk,
                             unsigned* s_scan, int* s_out, unsigned* sel,
                             int* remk_o) {
  constexpr int BPT = BINS / 256;
  const int t = threadIdx.x;
  if (t == 0) { s_out[0] = BINS - 1; s_out[1] = 0; }
  unsigned mb[BPT];
  unsigned s = 0;
#pragma unroll
  for (int i = 0; i < BPT; ++i) { mb[i] = h[t * BPT + i]; s += mb[i]; }
  unsigned incl = s;
  s_scan[t] = incl;
  __syncthreads();
  for (int off = 1; off < 256; off <<= 1) {
    const unsigned add = (t >= off) ? s_scan[t - off] : 0u;
    __syncthreads();
    incl += add;
    s_scan[t] = incl;
    __syncthreads();
  }
  const unsigned total = s_scan[255];
  const unsigned R = total - incl;
  if (remk > 0 && R < (unsigned)remk && R + s >= (unsigned)remk) {
    unsigned acc = R;
    int sel_i = t * BPT, rk = 0;
    bool done = false;
#pragma unroll
    for (int i = BPT - 1; i >= 0; --i) {
      if (!done && acc + mb[i] >= (unsigned)remk) {
        sel_i = t * BPT + i;
        rk = remk - (int)acc;
        done = true;
      }
      if (!done) acc += mb[i];
    }
    s_out[0] = sel_i;
    s_out[1] = rk;
  }
  __syncthreads();
  *sel = (unsigned)s_out[0];
  *remk_o = s_out[1];
  __syncthreads();
}

__global__ __launch_bounds__(256) void mbl_hist1(
    const float* __restrict__ conf_neg, const int* __restrict__ n_pos,
    const unsigned* __restrict__ hist0, unsigned* __restrict__ hist1, int P) {
  const int b = blockIdx.y;
  const int tid = threadIdx.x;
  __shared__ unsigned s_scan[256];
  __shared__ int s_out[2];
  __shared__ unsigned s_hist[4096];
  int K = 3 * n_pos[b];
  if (K > P) K = P;
  unsigned sel0;
  int rem0;
  block_select<4096>(hist0 + (size_t)b * 4096, K, s_scan, s_out, &sel0, &rem0);
  for (int i = tid; i < 4096; i += 256) s_hist[i] = 0u;
  __syncthreads();
  const float* row = conf_neg + (size_t)b * P;
  const int n4 = P >> 2;
  const int per = (n4 + (int)gridDim.x - 1) / (int)gridDim.x;
  const int s4 = blockIdx.x * per, e4 = min(s4 + per, n4);
  for (int i = s4 + tid; i < e4; i += 256) {
    const float4 v = ((const float4*)row)[i];
    unsigned u;
    u = __float_as_uint(v.x); if ((u >> 20) == sel0) atomicAdd(&s_hist[(u >> 8) & 4095u], 1u);
    u = __float_as_uint(v.y); if ((u >> 20) == sel0) atomicAdd(&s_hist[(u >> 8) & 4095u], 1u);
    u = __float_as_uint(v.z); if ((u >> 20) == sel0) atomicAdd(&s_hist[(u >> 8) & 4095u], 1u);
    u = __float_as_uint(v.w); if ((u >> 20) == sel0) atomicAdd(&s_hist[(u >> 8) & 4095u], 1u);
  }
  if (blockIdx.x == 0)
    for (int p = (n4 << 2) + tid; p < P; p += 256) {
      const unsigned u = __float_as_uint(row[p]);
      if ((u >> 20) == sel0) atomicAdd(&s_hist[(u >> 8) & 4095u], 1u);
    }
  __syncthreads();
  for (int i = tid; i < 4096; i += 256)
    if (s_hist[i]) atomicAdd(&hist1[(size_t)b * 4096 + i], s_hist[i]);
}

__global__ __launch_bounds__(256) void mbl_sum(
    const float* __restrict__ conf_neg, const int* __restrict__ n_pos,
    const unsigned* __restrict__ hist0, const unsigned* __restrict__ hist1,
    const double* __restrict__ pconf, const double* __restrict__ ploc,
    double* __restrict__ phard, unsigned* __restrict__ counter, int P, int B,
    float* __restrict__ out) {
  const int b = blockIdx.y;
  const int tid = threadIdx.x;
  __shared__ unsigned s_scan[256];
  __shared__ int s_out[2];
  int K = 3 * n_pos[b];
  if (K > P) K = P;
  unsigned sel0, sel1;
  int rem0, rem1;
  block_select<4096>(hist0 + (size_t)b * 4096, K, s_scan, s_out, &sel0, &rem0);
  block_select<4096>(hist1 + (size_t)b * 4096, rem0, s_scan, s_out, &sel1, &rem1);
  const unsigned pref24 = (sel0 << 12) | sel1;
  const unsigned tb = (pref24 << 8) | 0xFFu;
  const float* row = conf_neg + (size_t)b * P;
  const int n4 = P >> 2;
  const int per = (n4 + (int)gridDim.x - 1) / (int)gridDim.x;
  const int s4 = blockIdx.x * per, e4 = min(s4 + per, n4);
  double local = 0.0;
  for (int i = s4 + tid; i < e4; i += 256) {
    const float4 v = ((const float4*)row)[i];
    if (__float_as_uint(v.x) > tb) local += (double)v.x;
    if (__float_as_uint(v.y) > tb) local += (double)v.y;
    if (__float_as_uint(v.z) > tb) local += (double)v.z;
    if (__float_as_uint(v.w) > tb) local += (double)v.w;
  }
  if (blockIdx.x == 0) {
    for (int p = (n4 << 2) + tid; p < P; p += 256) {
      const float v = row[p];
      if (__float_as_uint(v) > tb) local += (double)v;
    }
    if (tid == 0 && rem1 > 0)
      local += (double)rem1 * (double)__uint_as_float((pref24 << 8) | 0x80u);
  }
  __shared__ double red[256];
  red[tid] = local;
  __syncthreads();
  for (int s = 128; s > 0; s >>= 1) {
    if (tid < s) red[tid] += red[tid + s];
    __syncthreads();
  }
  if (tid == 0) {
    if (red[0] != 0.0) atomicAdd(&phard[b], red[0]);
    __threadfence();
    const unsigned done = atomicAdd(counter, 1u);
    if (done == gridDim.x * gridDim.y - 1) {
      double tp = 0.0, cs = 0.0, ls = 0.0, hs = 0.0;
      for (int i = 0; i < B; ++i) {
        tp += (double)n_pos[i];
        cs += pconf[i];
        ls += ploc[i];
        hs += atomicAdd(&phard[i], 0.0);
      }
      out[0] = (float)((hs + cs) / tp);
      out[1] = (float)(ls / (tp * 6.0));
    }
  }
}

extern "C" void kernel_launch(void* const* d_in, const int* in_sizes, int n_in,
                              void* d_out, int out_size, void* d_ws, size_t ws_size,
                              hipStream_t stream) {
  const float* locs = (const float*)d_in[0];
  const float* scores = (const float*)d_in[1];
  const float* boxes = (const float*)d_in[2];
  const int* labels = (const int*)d_in[3];
  const float* priors = (const float*)d_in[4];

  const long long sz_locs = (long long)in_sizes[0];
  const long long sz_scores = (long long)in_sizes[1];
  const long long sz_priors = (long long)in_sizes[4];
  const int P = (int)(sz_priors / 6);
  const int B = (int)(sz_locs / sz_priors);
  const int n_obj = in_sizes[3] / B;
  const int C = (int)(sz_scores * 6 / sz_locs);

  char* ws = (char*)d_ws;
  size_t off = 0;
  double* pconf = (double*)(ws + off); off += (size_t)B * 8;
  double* ploc = (double*)(ws + off); off += (size_t)B * 8;
  double* phard = (double*)(ws + off); off += (size_t)B * 8;
  int* n_pos = (int*)(ws + off); off += ((size_t)B * 4 + 15) & ~(size_t)15;
  unsigned* counter = (unsigned*)(ws + off); off += 16;
  unsigned long long* prior_fo = (unsigned long long*)(ws + off);
  off += (size_t)B * 64 * 8;
  unsigned* hist0 = (unsigned*)(ws + off); off += (size_t)B * 4096 * 4;
  unsigned* hist1 = (unsigned*)(ws + off); off += (size_t)B * 4096 * 4;
  unsigned* cellhist = (unsigned*)(ws + off); off += (size_t)CELLS * 4;
  unsigned* cellcnt = (unsigned*)(ws + off); off += (size_t)CELLS * 4;
  unsigned* maxhalf = (unsigned*)(ws + off); off += 16;
  const size_t zero_bytes = off;
  unsigned* offs = (unsigned*)(ws + off); off += (size_t)CELLS * 4;
  unsigned* mask32 = (unsigned*)(ws + off); off += (size_t)B * CELLS * 4;
  float* conf_neg = (float*)(ws + off); off += ((size_t)B * P * 4 + 15) & ~(size_t)15;
  unsigned char* best_u8 = (unsigned char*)(ws + off);
  off += ((size_t)B * P + 15) & ~(size_t)15;
  off = (off + 15) & ~(size_t)15;
  float4* sorted = (float4*)(ws + off); off += (size_t)P * 2 * 16;
  (void)ws_size;

  hipMemsetAsync(d_ws, 0, zero_bytes, stream);

  const int pblk = (P + 255) / 256;
  mbl_s1<<<pblk, 256, 0, stream>>>(priors, cellhist, maxhalf, P);
  mbl_s2<<<1 + B, 256, 0, stream>>>(boxes, cellhist, offs, mask32, prior_fo,
                                    maxhalf, n_obj);
  mbl_s3<<<pblk, 256, 0, stream>>>(priors, offs, cellcnt, sorted, P);

  const int nblk = (P + TILE - 1) / TILE;
  const dim3 mgrid(nblk, B);
  if (n_obj <= 16) {
    mbl_match<16, true><<<mgrid, 256, 0, stream>>>(boxes, sorted, mask32,
                                                   prior_fo, best_u8, P, n_obj);
  } else if (n_obj <= 32) {
    mbl_match<32, true><<<mgrid, 256, 0, stream>>>(boxes, sorted, mask32,
                                                   prior_fo, best_u8, P, n_obj);
  } else {
    mbl_match<64, false><<<mgrid, 256, 0, stream>>>(boxes, sorted, mask32,
                                                    prior_fo, best_u8, P, n_obj);
  }

  const dim3 lgrid(LB, B);
  if (C == 2)
    mbl_loss<2><<<lgrid, 256, 0, stream>>>(locs, scores, boxes, labels, priors,
                                           prior_fo, best_u8, conf_neg, hist0, n_pos,
                                           pconf, ploc, P, n_obj, C);
  else
    mbl_loss<0><<<lgrid, 256, 0, stream>>>(locs, scores, boxes, labels, priors,
                                           prior_fo, best_u8, conf_neg, hist0, n_pos,
                                           pconf, ploc, P, n_obj, C);

  mbl_hist1<<<lgrid, 256, 0, stream>>>(conf_neg, n_pos, hist0, hist1, P);
  mbl_sum<<<lgrid, 256, 0, stream>>>(conf_neg, n_pos, hist0, hist1, pconf, ploc,
                                     phard, counter, P, B, (float*)d_out);
}